// Round 11
// baseline (389.092 us; speedup 1.0000x reference)
//
#include <hip/hip_runtime.h>
#include <stdint.h>

// SpikingTransformer block, bf16 MFMA. R7 (5th submit, unchanged): 2-phase
// pipelined GEMM K-loop (double-buffered LDS, stage(t+1) + B-prefetch
// overlapped with MFMA(t), ONE barrier per K-step). p-GEMM residual bf16 xb.
// B=16, N=1024, C=512, H=8, hd=64, HID=2048, M=B*N=16384.
//
// Workspace (MB offsets): 0 Wqkv(1.5) | 2 Wp(.5) | 3 W1(2) | 5 W2(2) | 7 BN |
//   8 xb(16.8)->x1 | 25 qb(16.8, o aliases) | 42 kb | 59 vb | 76 h(67.1)->143 |
//   150 ktvB(2)

typedef __attribute__((ext_vector_type(8))) short short8;
typedef __attribute__((ext_vector_type(4))) short short4v;
typedef __attribute__((ext_vector_type(4))) float f32x4;
typedef __attribute__((ext_vector_type(4))) unsigned int uint4v;

#define MFMA_BF16 __builtin_amdgcn_mfma_f32_16x16x32_bf16

__device__ __forceinline__ float bf2f(unsigned short u) {
    return __uint_as_float(((unsigned int)u) << 16);
}
__device__ __forceinline__ unsigned short f2bf(float f) {
    unsigned int b = __float_as_uint(f);
    return (unsigned short)((b + 0x7fffu + ((b >> 16) & 1u)) >> 16);
}
__device__ __forceinline__ void gl_lds16(const void* g, void* l) {
    __builtin_amdgcn_global_load_lds(
        (const __attribute__((address_space(1))) void*)g,
        (__attribute__((address_space(3))) void*)l, 16, 0, 0);
}

// ---------------- BN fold ----------------
__global__ __launch_bounds__(256) void prep_bn(
    const float* __restrict__ bias, const float* __restrict__ g,
    const float* __restrict__ be,   const float* __restrict__ m,
    const float* __restrict__ v,
    float* __restrict__ sc, float* __restrict__ sh, int n)
{
    int i = blockIdx.x * 256 + threadIdx.x;
    if (i < n) {
        float s = g[i] * rsqrtf(v[i] + 1e-5f);
        sc[i] = s;
        sh[i] = (bias[i] - m[i]) * s + be[i];
    }
}

// ---------------- x -> bf16 ----------------
__global__ __launch_bounds__(256) void to_bf16(
    const float* __restrict__ in, unsigned short* __restrict__ out, int n8)
{
    int i = blockIdx.x * 256 + threadIdx.x;
    if (i >= n8) return;
    const float4* p = (const float4*)in + (size_t)i * 2;
    float4 a = p[0], b = p[1];
    short8 r = {(short)f2bf(a.x), (short)f2bf(a.y), (short)f2bf(a.z), (short)f2bf(a.w),
                (short)f2bf(b.x), (short)f2bf(b.y), (short)f2bf(b.z), (short)f2bf(b.w)};
    ((short8*)out)[i] = r;
}

// -------- pack W (NxK fp32) into MFMA B-fragment order --------
__global__ __launch_bounds__(256) void prep_w(
    const float* __restrict__ W, unsigned short* __restrict__ ph, int N, int K)
{
    int tid = blockIdx.x * 256 + threadIdx.x;
    int KC = K >> 5;
    int total = (N >> 4) * KC * 64;
    if (tid >= total) return;
    int lane = tid & 63;
    int blk  = tid >> 6;
    int kc   = blk % KC;
    int n16  = blk / KC;
    int n  = (n16 << 4) + (lane & 15);
    int k0 = (kc << 5) + ((lane >> 4) << 3);
    const float* src = W + (size_t)n * K + k0;
    size_t dst = ((size_t)blk << 9) + (size_t)lane * 8;
#pragma unroll
    for (int j = 0; j < 8; ++j) ph[dst + j] = f2bf(src[j]);
}

// ---------------- bf16 GEMM + BN + ReLU (+ residual), 2-phase ----------------
// out = relu((A @ W^T) * sc + sh) [+ res]
// NT: block N-tile (128/64). RESMODE: 0 none, 1 fp32 res, 2 bf16 res.
// OUTMODE: 0 bf16, 1 fp32, 2 qkv-split.
template<int NT, int RESMODE, int OUTMODE>
__global__ __launch_bounds__(256) void gemm_bf16(
    const unsigned short* __restrict__ Ag, const unsigned short* __restrict__ Wg,
    const float* __restrict__ sc, const float* __restrict__ sh,
    const float* __restrict__ resf, const unsigned short* __restrict__ resb,
    float* __restrict__ outf, unsigned short* __restrict__ outb,
    unsigned short* __restrict__ oq, unsigned short* __restrict__ ok2,
    unsigned short* __restrict__ ov, int M, int N, int K)
{
    constexpr int NF = NT / 32;
    __shared__ unsigned short As[2][128 * 32];   // double-buffered A tile

    const int t    = threadIdx.x;
    const int lane = t & 63;
    const int w    = t >> 6;
    const int wm   = w >> 1, wn = w & 1;
    const int KC   = K >> 5;

    const int nx  = gridDim.x;
    const int nwg = nx * gridDim.y;
    int bid = blockIdx.y * nx + blockIdx.x;
    bid = (bid & 7) * (nwg >> 3) + (bid >> 3);
    const int m0 = (bid / nx) * 128;
    const int n0 = (bid % nx) * NT;

    // A staging addresses (source pre-swizzled, as R5/R6: 0 bank conflicts)
    const int sr  = lane >> 2;
    const int kbu = (lane & 3) ^ ((lane >> 3) & 3);
    const unsigned short* sA0 = Ag + (size_t)(m0 + w * 32 + sr) * K + kbu * 8;
    const unsigned short* sA1 = sA0 + (size_t)16 * K;
    const int dOf0 = (w * 32) * 32;              // LDS short-offsets (wave-uniform)
    const int dOf1 = (w * 32 + 16) * 32;

    // B fragment pointers (advance 512 elems per kc)
    const unsigned short* pB[NF];
#pragma unroll
    for (int nf = 0; nf < NF; ++nf) {
        const int n16 = (n0 >> 4) + wn * (NT / 32) + nf;
        pB[nf] = Wg + (((size_t)n16 * (K >> 5)) << 9) + (size_t)lane * 8;
    }

    // A fragment LDS offsets
    const int fr = lane & 15, fk = lane >> 4;
    const int funit = fk ^ ((fr >> 1) & 3);
    int aoff[4];
#pragma unroll
    for (int mi = 0; mi < 4; ++mi)
        aoff[mi] = (wm * 64 + mi * 16 + fr) * 32 + funit * 8;

    f32x4 acc[4][NF];
#pragma unroll
    for (int i = 0; i < 4; ++i)
#pragma unroll
        for (int j = 0; j < NF; ++j) acc[i][j] = f32x4{0.f, 0.f, 0.f, 0.f};

    // ---- prologue: stage tile 0, load B(0) ----
    gl_lds16(sA0, &As[0][dOf0]); gl_lds16(sA1, &As[0][dOf1]);
    sA0 += 32; sA1 += 32;
    short8 bcur[NF], bnext[NF];
#pragma unroll
    for (int nf = 0; nf < NF; ++nf) {
        bcur[nf] = *(const short8*)pB[nf];
        pB[nf] += 512;
    }
    __syncthreads();                 // drains vmcnt: buf0 + B(0) ready

    int cur = 0;
    for (int kc = 0; kc < KC; ++kc) {
        if (kc + 1 < KC) {           // issue next-tile stage + B prefetch
            gl_lds16(sA0, &As[cur ^ 1][dOf0]);
            gl_lds16(sA1, &As[cur ^ 1][dOf1]);
            sA0 += 32; sA1 += 32;
#pragma unroll
            for (int nf = 0; nf < NF; ++nf) {
                bnext[nf] = *(const short8*)pB[nf];
                pB[nf] += 512;
            }
        }
        short8 ah[4];
#pragma unroll
        for (int mi = 0; mi < 4; ++mi)
            ah[mi] = *(const short8*)&As[cur][aoff[mi]];
#pragma unroll
        for (int mi = 0; mi < 4; ++mi)
#pragma unroll
            for (int nf = 0; nf < NF; ++nf)
                acc[mi][nf] = MFMA_BF16(ah[mi], bcur[nf], acc[mi][nf], 0, 0, 0);
        __syncthreads();             // one drain/K-step: stage(t+1)+B(t+1) landed,
                                     // all waves done reading buf[cur]
#pragma unroll
        for (int nf = 0; nf < NF; ++nf) bcur[nf] = bnext[nf];
        cur ^= 1;
    }

    // epilogue: C/D layout col = lane&15, row = (lane>>4)*4 + reg (m89)
    const int erow4 = fk * 4;
#pragma unroll
    for (int nf = 0; nf < NF; ++nf) {
        const int col = n0 + wn * (NT / 2) + nf * 16 + fr;
        const float scv = sc[col], shv = sh[col];
        unsigned short* qsplit = nullptr;
        int lc = 0;
        if (OUTMODE == 2) {
            const int tsel = col >> 9;
            qsplit = (tsel == 0) ? oq : (tsel == 1) ? ok2 : ov;
            lc = col & 511;
        }
#pragma unroll
        for (int mi = 0; mi < 4; ++mi) {
            const int rbase = m0 + wm * 64 + mi * 16 + erow4;
#pragma unroll
            for (int r = 0; r < 4; ++r) {
                const size_t row = (size_t)(rbase + r);
                float z = fmaf(acc[mi][nf][r], scv, shv);
                z = fmaxf(z, 0.f);
                if (RESMODE == 1) z += resf[row * N + col];
                if (RESMODE == 2) z += bf2f(resb[row * N + col]);
                if (OUTMODE == 0)      outb[row * N + col] = f2bf(z);
                else if (OUTMODE == 1) outf[row * N + col] = z;
                else                   qsplit[row * 512 + lc] = f2bf(z);
            }
        }
    }
}

// ---------------- attn phase A: partial ktv, packed B-frag emit ----------------
// (unchanged from R6 -- attn no longer in top-5)
__global__ __launch_bounds__(64) void attn_kv(
    const unsigned short* __restrict__ k, const unsigned short* __restrict__ v,
    unsigned short* __restrict__ ktvB)
{
    __shared__ unsigned short kN[32 * 66];
    __shared__ unsigned short vN[32 * 66];
    __shared__ float red[64 * 65];

    const int l  = threadIdx.x;
    const int bh = blockIdx.x >> 1;
    const int h1 = blockIdx.x & 1;
    const int b = bh >> 3, h = bh & 7;
    const int c8 = l & 7;
    const int rh = l >> 3;
    const int c  = l & 15, nh = l >> 4;

    f32x4 acc[4][4];
#pragma unroll
    for (int i = 0; i < 4; ++i)
#pragma unroll
        for (int j = 0; j < 4; ++j) acc[i][j] = f32x4{0.f, 0.f, 0.f, 0.f};

    const size_t gbase = ((size_t)b * 1024 + (size_t)h1 * 512) * 512 + (size_t)h * 64;

    for (int t = 0; t < 16; ++t) {
        short8 kr[4], vr[4];
#pragma unroll
        for (int q = 0; q < 4; ++q) {
            const int n = 8 * q + rh;
            const size_t ga = gbase + (size_t)(t * 32 + n) * 512 + c8 * 8;
            kr[q] = *(const short8*)(k + ga);
            vr[q] = *(const short8*)(v + ga);
        }
        __syncthreads();
#pragma unroll
        for (int q = 0; q < 4; ++q) {
            const int n = 8 * q + rh;
            unsigned int* pk = (unsigned int*)&kN[n * 66 + c8 * 8];
            unsigned int* pv = (unsigned int*)&vN[n * 66 + c8 * 8];
            uint4v ku = *(const uint4v*)&kr[q];
            uint4v vu = *(const uint4v*)&vr[q];
#pragma unroll
            for (int w2 = 0; w2 < 4; ++w2) { pk[w2] = ku[w2]; pv[w2] = vu[w2]; }
        }
        __syncthreads();

        short8 aF[4], bF[4];
#pragma unroll
        for (int it = 0; it < 4; ++it)
#pragma unroll
            for (int jj = 0; jj < 8; ++jj)
                aF[it][jj] = (short)kN[(8 * nh + jj) * 66 + it * 16 + c];
#pragma unroll
        for (int jt = 0; jt < 4; ++jt)
#pragma unroll
            for (int jj = 0; jj < 8; ++jj)
                bF[jt][jj] = (short)vN[(8 * nh + jj) * 66 + jt * 16 + c];
#pragma unroll
        for (int it = 0; it < 4; ++it)
#pragma unroll
            for (int jt = 0; jt < 4; ++jt)
                acc[it][jt] = MFMA_BF16(aF[it], bF[jt], acc[it][jt], 0, 0, 0);
    }

#pragma unroll
    for (int it = 0; it < 4; ++it)
#pragma unroll
        for (int jt = 0; jt < 4; ++jt)
#pragma unroll
            for (int r = 0; r < 4; ++r)
                red[(it * 16 + nh * 4 + r) * 65 + jt * 16 + c] = acc[it][jt][r];
    __syncthreads();

    unsigned short* dstb = ktvB + (size_t)bh * 8192;
#pragma unroll
    for (int j16 = 0; j16 < 4; ++j16)
#pragma unroll
        for (int dcl = 0; dcl < 2; ++dcl) {
            short8 o8;
#pragma unroll
            for (int jj = 0; jj < 8; ++jj)
                o8[jj] = (short)f2bf(red[(dcl * 32 + 8 * nh + jj) * 65 + j16 * 16 + c] * 0.125f);
            *(short8*)(dstb + (size_t)(j16 * 4 + (2 * h1 + dcl)) * 512 + l * 8) = o8;
        }
}

// ---------------- attn phase B: o = relu(q @ [P0;P1]) ---------------- (as R6)
__global__ __launch_bounds__(256) void attn_qo(
    const unsigned short* __restrict__ q, const unsigned short* __restrict__ ktvB,
    unsigned short* __restrict__ o)
{
    __shared__ unsigned short qS[128 * 64];

    int bid = blockIdx.x;
    bid = (bid & 7) * 128 + (bid >> 3);
    const int bh = bid >> 3, mt = bid & 7;
    const int b = bh >> 3, h = bh & 7;
    const size_t Mbase = (size_t)b * 1024 + (size_t)mt * 128;
    const int t = threadIdx.x, l = t & 63, w = t >> 6;
    const int c = l & 15, nh = l >> 4;

#pragma unroll
    for (int qq = 0; qq < 4; ++qq) {
        const int r  = qq * 32 + w * 8 + (l >> 3);
        const int cl = (l & 7) ^ (r & 7);
        gl_lds16(q + (Mbase + r) * 512 + h * 64 + cl * 8,
                 &qS[(qq * 32 + w * 8) * 64]);
    }
    __syncthreads();

    const unsigned short* pB = ktvB + (size_t)bh * 8192 + (size_t)l * 8;

    f32x4 acc[2][4];
#pragma unroll
    for (int i = 0; i < 2; ++i)
#pragma unroll
        for (int j = 0; j < 4; ++j) acc[i][j] = f32x4{0.f, 0.f, 0.f, 0.f};

#pragma unroll
    for (int ks = 0; ks < 4; ++ks) {
        short8 aF[2], bF[4];
#pragma unroll
        for (int it = 0; it < 2; ++it) {
            const int ra   = w * 32 + it * 16 + c;
            const int phys = (((ks & 1) * 4) + nh) ^ (c & 7);
            aF[it] = *(const short8*)&qS[ra * 64 + phys * 8];
        }
#pragma unroll
        for (int jt = 0; jt < 4; ++jt)
            bF[jt] = *(const short8*)(pB + (size_t)(jt * 4 + ks) * 512);
#pragma unroll
        for (int it = 0; it < 2; ++it)
#pragma unroll
            for (int jt = 0; jt < 4; ++jt)
                acc[it][jt] = MFMA_BF16(aF[it], bF[jt], acc[it][jt], 0, 0, 0);
    }

#pragma unroll
    for (int it = 0; it < 2; ++it)
#pragma unroll
        for (int jt = 0; jt < 4; ++jt)
#pragma unroll
            for (int r = 0; r < 4; ++r) {
                const size_t row = Mbase + w * 32 + it * 16 + nh * 4 + r;
                o[row * 512 + h * 64 + jt * 16 + c] =
                    f2bf(fmaxf(acc[it][jt][r], 0.f));
            }
}

extern "C" void kernel_launch(void* const* d_in, const int* in_sizes, int n_in,
                              void* d_out, int out_size, void* d_ws, size_t ws_size,
                              hipStream_t stream)
{
    (void)in_sizes; (void)n_in; (void)out_size; (void)ws_size;
    const float* x = (const float*)d_in[0];
    auto P = [&](int i) { return (const float*)d_in[i]; };

    char* wsb = (char*)d_ws;
    const size_t MB = 1024 * 1024;
    auto US = [&](size_t off) { return (unsigned short*)(wsb + off); };

    unsigned short* Wqkv = US(0);
    unsigned short* Wp   = US(2 * MB);
    unsigned short* W1   = US(3 * MB);
    unsigned short* W2   = US(5 * MB);

    float* bn = (float*)(wsb + 7 * MB);
    float* sc_qkv = bn;          float* sh_qkv = bn + 1536;
    float* sc_p = bn + 3072;     float* sh_p = bn + 3584;
    float* sc_1 = bn + 4096;     float* sh_1 = bn + 6144;
    float* sc_2 = bn + 8192;     float* sh_2 = bn + 8704;

    unsigned short* xb = US(8 * MB);
    unsigned short* qb = US(25 * MB);      // o aliases q
    unsigned short* kb = US(42 * MB);
    unsigned short* vb = US(59 * MB);
    unsigned short* hb = US(76 * MB);
    unsigned short* x1 = xb;
    unsigned short* ktvB = US(150 * MB);

    prep_bn<<<2, 256, 0, stream>>>(P(2),  P(3),  P(4),  P(5),  P(6),  sc_qkv,        sh_qkv,        512);
    prep_bn<<<2, 256, 0, stream>>>(P(8),  P(9),  P(10), P(11), P(12), sc_qkv + 512,  sh_qkv + 512,  512);
    prep_bn<<<2, 256, 0, stream>>>(P(14), P(15), P(16), P(17), P(18), sc_qkv + 1024, sh_qkv + 1024, 512);
    prep_bn<<<2, 256, 0, stream>>>(P(20), P(21), P(22), P(23), P(24), sc_p, sh_p, 512);
    prep_bn<<<8, 256, 0, stream>>>(P(26), P(27), P(28), P(29), P(30), sc_1, sh_1, 2048);
    prep_bn<<<2, 256, 0, stream>>>(P(32), P(33), P(34), P(35), P(36), sc_2, sh_2, 512);

    to_bf16<<<4096, 256, 0, stream>>>(x, xb, 16384 * 512 / 8);

    prep_w<<<128, 256, 0, stream>>>(P(1),  Wqkv,          512, 512);
    prep_w<<<128, 256, 0, stream>>>(P(7),  Wqkv + 262144, 512, 512);
    prep_w<<<128, 256, 0, stream>>>(P(13), Wqkv + 524288, 512, 512);
    prep_w<<<128, 256, 0, stream>>>(P(19), Wp, 512, 512);
    prep_w<<<512, 256, 0, stream>>>(P(25), W1, 2048, 512);
    prep_w<<<512, 256, 0, stream>>>(P(31), W2, 512, 2048);

    const dim3 blk(256);

    gemm_bf16<128, 0, 2><<<dim3(12, 128), blk, 0, stream>>>(
        xb, Wqkv, sc_qkv, sh_qkv, nullptr, nullptr,
        nullptr, nullptr, qb, kb, vb, 16384, 1536, 512);

    attn_kv<<<256, 64, 0, stream>>>(kb, vb, ktvB);
    attn_qo<<<1024, blk, 0, stream>>>(qb, ktvB, qb);   // o -> qb

    // x1 = bf16(x) + relu(bn(o @ p_w^T))  -- residual from xb (bf16), saves 32MB fetch
    gemm_bf16<64, 2, 0><<<dim3(8, 128), blk, 0, stream>>>(
        qb, Wp, sc_p, sh_p, nullptr, xb,
        nullptr, x1, nullptr, nullptr, nullptr, 16384, 512, 512);

    gemm_bf16<128, 0, 0><<<dim3(16, 128), blk, 0, stream>>>(
        x1, W1, sc_1, sh_1, nullptr, nullptr,
        nullptr, hb, nullptr, nullptr, nullptr, 16384, 2048, 512);

    gemm_bf16<64, 2, 1><<<dim3(8, 128), blk, 0, stream>>>(
        hb, W2, sc_2, sh_2, nullptr, x1,
        (float*)d_out, nullptr, nullptr, nullptr, nullptr, 16384, 512, 2048);
}

// Round 12
// 361.032 us; speedup vs baseline: 1.0777x; 1.0777x over previous
//
#include <hip/hip_runtime.h>
#include <stdint.h>

// SpikingTransformer block, bf16 MFMA. R11: 2-phase pipeline with BOTH A and B
// staged via global_load_lds into double-buffered LDS (B prefetch moved out of
// registers -- R7's bnext[] pushed total regs 128->136, halving waves/SIMD).
// One barrier per K-step, placed after the MFMA phase.
// B=16, N=1024, C=512, H=8, hd=64, HID=2048, M=B*N=16384.
//
// Workspace (MB offsets): 0 Wqkv(1.5) | 2 Wp(.5) | 3 W1(2) | 5 W2(2) | 7 BN |
//   8 xb(16.8)->x1 | 25 qb(16.8, o aliases) | 42 kb | 59 vb | 76 h(67.1)->143 |
//   150 ktvB(2)

typedef __attribute__((ext_vector_type(8))) short short8;
typedef __attribute__((ext_vector_type(4))) short short4v;
typedef __attribute__((ext_vector_type(4))) float f32x4;
typedef __attribute__((ext_vector_type(4))) unsigned int uint4v;

#define MFMA_BF16 __builtin_amdgcn_mfma_f32_16x16x32_bf16

__device__ __forceinline__ float bf2f(unsigned short u) {
    return __uint_as_float(((unsigned int)u) << 16);
}
__device__ __forceinline__ unsigned short f2bf(float f) {
    unsigned int b = __float_as_uint(f);
    return (unsigned short)((b + 0x7fffu + ((b >> 16) & 1u)) >> 16);
}
__device__ __forceinline__ void gl_lds16(const void* g, void* l) {
    __builtin_amdgcn_global_load_lds(
        (const __attribute__((address_space(1))) void*)g,
        (__attribute__((address_space(3))) void*)l, 16, 0, 0);
}

// ---------------- BN fold ----------------
__global__ __launch_bounds__(256) void prep_bn(
    const float* __restrict__ bias, const float* __restrict__ g,
    const float* __restrict__ be,   const float* __restrict__ m,
    const float* __restrict__ v,
    float* __restrict__ sc, float* __restrict__ sh, int n)
{
    int i = blockIdx.x * 256 + threadIdx.x;
    if (i < n) {
        float s = g[i] * rsqrtf(v[i] + 1e-5f);
        sc[i] = s;
        sh[i] = (bias[i] - m[i]) * s + be[i];
    }
}

// ---------------- x -> bf16 ----------------
__global__ __launch_bounds__(256) void to_bf16(
    const float* __restrict__ in, unsigned short* __restrict__ out, int n8)
{
    int i = blockIdx.x * 256 + threadIdx.x;
    if (i >= n8) return;
    const float4* p = (const float4*)in + (size_t)i * 2;
    float4 a = p[0], b = p[1];
    short8 r = {(short)f2bf(a.x), (short)f2bf(a.y), (short)f2bf(a.z), (short)f2bf(a.w),
                (short)f2bf(b.x), (short)f2bf(b.y), (short)f2bf(b.z), (short)f2bf(b.w)};
    ((short8*)out)[i] = r;
}

// -------- pack W (NxK fp32) into MFMA B-fragment order --------
__global__ __launch_bounds__(256) void prep_w(
    const float* __restrict__ W, unsigned short* __restrict__ ph, int N, int K)
{
    int tid = blockIdx.x * 256 + threadIdx.x;
    int KC = K >> 5;
    int total = (N >> 4) * KC * 64;
    if (tid >= total) return;
    int lane = tid & 63;
    int blk  = tid >> 6;
    int kc   = blk % KC;
    int n16  = blk / KC;
    int n  = (n16 << 4) + (lane & 15);
    int k0 = (kc << 5) + ((lane >> 4) << 3);
    const float* src = W + (size_t)n * K + k0;
    size_t dst = ((size_t)blk << 9) + (size_t)lane * 8;
#pragma unroll
    for (int j = 0; j < 8; ++j) ph[dst + j] = f2bf(src[j]);
}

// ---------------- bf16 GEMM + BN + ReLU (+ residual), 2-phase ----------------
// out = relu((A @ W^T) * sc + sh) [+ res]
// NT: block N-tile (128/64). RESMODE: 0 none, 1 fp32 res, 2 bf16 res.
// OUTMODE: 0 bf16, 1 fp32, 2 qkv-split.
template<int NT, int RESMODE, int OUTMODE>
__global__ __launch_bounds__(256) void gemm_bf16(
    const unsigned short* __restrict__ Ag, const unsigned short* __restrict__ Wg,
    const float* __restrict__ sc, const float* __restrict__ sh,
    const float* __restrict__ resf, const unsigned short* __restrict__ resb,
    float* __restrict__ outf, unsigned short* __restrict__ outb,
    unsigned short* __restrict__ oq, unsigned short* __restrict__ ok2,
    unsigned short* __restrict__ ov, int M, int N, int K)
{
    constexpr int NF  = NT / 32;        // B-frags per wave
    constexpr int NFB = 2 * NF;         // B-frag blocks per block tile
    constexpr int FPW = NFB / 4;        // frag blocks staged per wave (2 or 1)
    __shared__ unsigned short As[2][128 * 32];     // A tile dbuf (8KB each)
    __shared__ unsigned short Bs[2][NFB * 512];    // B frag dbuf (8/4KB each)

    const int t    = threadIdx.x;
    const int lane = t & 63;
    const int w    = t >> 6;
    const int wm   = w >> 1, wn = w & 1;
    const int KC   = K >> 5;

    // bijective XCD swizzle (all grids %8==0)
    const int nx  = gridDim.x;
    const int nwg = nx * gridDim.y;
    int bid = blockIdx.y * nx + blockIdx.x;
    bid = (bid & 7) * (nwg >> 3) + (bid >> 3);
    const int m0 = (bid / nx) * 128;
    const int n0 = (bid % nx) * NT;

    // A staging (pre-swizzled source == read swizzle; 0 conflicts since R5)
    const int sr  = lane >> 2;
    const int kbu = (lane & 3) ^ ((lane >> 3) & 3);
    const unsigned short* sA0 = Ag + (size_t)(m0 + w * 32 + sr) * K + kbu * 8;
    const unsigned short* sA1 = sA0 + (size_t)16 * K;
    const int dOf0 = (w * 32) * 32;     // wave-uniform LDS short-offsets
    const int dOf1 = (w * 32 + 16) * 32;

    // B staging: wave w stages frag blocks [w*FPW, w*FPW+FPW); lane -> lane*16B
    // (packed layout IS the gl_lds shape: wave-uniform base + lane*16B)
    const unsigned short* sB[FPW];
#pragma unroll
    for (int s = 0; s < FPW; ++s) {
        const int f = w * FPW + s;
        sB[s] = Wg + (((size_t)(((n0 >> 4) + f) * KC)) << 9) + (size_t)lane * 8;
    }

    // A fragment LDS offsets (shorts)
    const int fr = lane & 15, fk = lane >> 4;
    const int funit = fk ^ ((fr >> 1) & 3);
    int aoff[4];
#pragma unroll
    for (int mi = 0; mi < 4; ++mi)
        aoff[mi] = (wm * 64 + mi * 16 + fr) * 32 + funit * 8;
    // B fragment LDS offsets: linear lane*16B within frag block (conflict-free)
    int boff[NF];
#pragma unroll
    for (int nf = 0; nf < NF; ++nf)
        boff[nf] = (wn * NF + nf) * 512 + lane * 8;

    f32x4 acc[4][NF];
#pragma unroll
    for (int i = 0; i < 4; ++i)
#pragma unroll
        for (int j = 0; j < NF; ++j) acc[i][j] = f32x4{0.f, 0.f, 0.f, 0.f};

    // ---- prologue: stage tile 0 (A and B) ----
    gl_lds16(sA0, &As[0][dOf0]); gl_lds16(sA1, &As[0][dOf1]);
    sA0 += 32; sA1 += 32;
#pragma unroll
    for (int s = 0; s < FPW; ++s) {
        gl_lds16(sB[s], &Bs[0][(w * FPW + s) * 512]);
        sB[s] += 512;
    }
    __syncthreads();                    // vmcnt drain: tile 0 ready

    int cur = 0;
    for (int kc = 0; kc < KC; ++kc) {
        if (kc + 1 < KC) {              // issue next-tile stage (A + B)
            gl_lds16(sA0, &As[cur ^ 1][dOf0]);
            gl_lds16(sA1, &As[cur ^ 1][dOf1]);
            sA0 += 32; sA1 += 32;
#pragma unroll
            for (int s = 0; s < FPW; ++s) {
                gl_lds16(sB[s], &Bs[cur ^ 1][(w * FPW + s) * 512]);
                sB[s] += 512;
            }
        }
        short8 ah[4], bh[NF];
#pragma unroll
        for (int mi = 0; mi < 4; ++mi)
            ah[mi] = *(const short8*)&As[cur][aoff[mi]];
#pragma unroll
        for (int nf = 0; nf < NF; ++nf)
            bh[nf] = *(const short8*)&Bs[cur][boff[nf]];
#pragma unroll
        for (int mi = 0; mi < 4; ++mi)
#pragma unroll
            for (int nf = 0; nf < NF; ++nf)
                acc[mi][nf] = MFMA_BF16(ah[mi], bh[nf], acc[mi][nf], 0, 0, 0);
        __syncthreads();                // one drain/K-step after compute phase
        cur ^= 1;
    }

    // epilogue: C/D layout col = lane&15, row = (lane>>4)*4 + reg (m89)
    const int erow4 = fk * 4;
#pragma unroll
    for (int nf = 0; nf < NF; ++nf) {
        const int col = n0 + wn * (NT / 2) + nf * 16 + fr;
        const float scv = sc[col], shv = sh[col];
        unsigned short* qsplit = nullptr;
        int lc = 0;
        if (OUTMODE == 2) {
            const int tsel = col >> 9;
            qsplit = (tsel == 0) ? oq : (tsel == 1) ? ok2 : ov;
            lc = col & 511;
        }
#pragma unroll
        for (int mi = 0; mi < 4; ++mi) {
            const int rbase = m0 + wm * 64 + mi * 16 + erow4;
#pragma unroll
            for (int r = 0; r < 4; ++r) {
                const size_t row = (size_t)(rbase + r);
                float z = fmaf(acc[mi][nf][r], scv, shv);
                z = fmaxf(z, 0.f);
                if (RESMODE == 1) z += resf[row * N + col];
                if (RESMODE == 2) z += bf2f(resb[row * N + col]);
                if (OUTMODE == 0)      outb[row * N + col] = f2bf(z);
                else if (OUTMODE == 1) outf[row * N + col] = z;
                else                   qsplit[row * 512 + lc] = f2bf(z);
            }
        }
    }
}

// ---------------- attn phase A: partial ktv, packed B-frag emit ----------------
__global__ __launch_bounds__(64) void attn_kv(
    const unsigned short* __restrict__ k, const unsigned short* __restrict__ v,
    unsigned short* __restrict__ ktvB)
{
    __shared__ unsigned short kN[32 * 66];
    __shared__ unsigned short vN[32 * 66];
    __shared__ float red[64 * 65];

    const int l  = threadIdx.x;
    const int bh = blockIdx.x >> 1;
    const int h1 = blockIdx.x & 1;
    const int b = bh >> 3, h = bh & 7;
    const int c8 = l & 7;
    const int rh = l >> 3;
    const int c  = l & 15, nh = l >> 4;

    f32x4 acc[4][4];
#pragma unroll
    for (int i = 0; i < 4; ++i)
#pragma unroll
        for (int j = 0; j < 4; ++j) acc[i][j] = f32x4{0.f, 0.f, 0.f, 0.f};

    const size_t gbase = ((size_t)b * 1024 + (size_t)h1 * 512) * 512 + (size_t)h * 64;

    for (int t = 0; t < 16; ++t) {
        short8 kr[4], vr[4];
#pragma unroll
        for (int q = 0; q < 4; ++q) {
            const int n = 8 * q + rh;
            const size_t ga = gbase + (size_t)(t * 32 + n) * 512 + c8 * 8;
            kr[q] = *(const short8*)(k + ga);
            vr[q] = *(const short8*)(v + ga);
        }
        __syncthreads();
#pragma unroll
        for (int q = 0; q < 4; ++q) {
            const int n = 8 * q + rh;
            unsigned int* pk = (unsigned int*)&kN[n * 66 + c8 * 8];
            unsigned int* pv = (unsigned int*)&vN[n * 66 + c8 * 8];
            uint4v ku = *(const uint4v*)&kr[q];
            uint4v vu = *(const uint4v*)&vr[q];
#pragma unroll
            for (int w2 = 0; w2 < 4; ++w2) { pk[w2] = ku[w2]; pv[w2] = vu[w2]; }
        }
        __syncthreads();

        short8 aF[4], bF[4];
#pragma unroll
        for (int it = 0; it < 4; ++it)
#pragma unroll
            for (int jj = 0; jj < 8; ++jj)
                aF[it][jj] = (short)kN[(8 * nh + jj) * 66 + it * 16 + c];
#pragma unroll
        for (int jt = 0; jt < 4; ++jt)
#pragma unroll
            for (int jj = 0; jj < 8; ++jj)
                bF[jt][jj] = (short)vN[(8 * nh + jj) * 66 + jt * 16 + c];
#pragma unroll
        for (int it = 0; it < 4; ++it)
#pragma unroll
            for (int jt = 0; jt < 4; ++jt)
                acc[it][jt] = MFMA_BF16(aF[it], bF[jt], acc[it][jt], 0, 0, 0);
    }

#pragma unroll
    for (int it = 0; it < 4; ++it)
#pragma unroll
        for (int jt = 0; jt < 4; ++jt)
#pragma unroll
            for (int r = 0; r < 4; ++r)
                red[(it * 16 + nh * 4 + r) * 65 + jt * 16 + c] = acc[it][jt][r];
    __syncthreads();

    unsigned short* dstb = ktvB + (size_t)bh * 8192;
#pragma unroll
    for (int j16 = 0; j16 < 4; ++j16)
#pragma unroll
        for (int dcl = 0; dcl < 2; ++dcl) {
            short8 o8;
#pragma unroll
            for (int jj = 0; jj < 8; ++jj)
                o8[jj] = (short)f2bf(red[(dcl * 32 + 8 * nh + jj) * 65 + j16 * 16 + c] * 0.125f);
            *(short8*)(dstb + (size_t)(j16 * 4 + (2 * h1 + dcl)) * 512 + l * 8) = o8;
        }
}

// ---------------- attn phase B: o = relu(q @ [P0;P1]) ----------------
__global__ __launch_bounds__(256) void attn_qo(
    const unsigned short* __restrict__ q, const unsigned short* __restrict__ ktvB,
    unsigned short* __restrict__ o)
{
    __shared__ unsigned short qS[128 * 64];

    int bid = blockIdx.x;
    bid = (bid & 7) * 128 + (bid >> 3);
    const int bh = bid >> 3, mt = bid & 7;
    const int b = bh >> 3, h = bh & 7;
    const size_t Mbase = (size_t)b * 1024 + (size_t)mt * 128;
    const int t = threadIdx.x, l = t & 63, w = t >> 6;
    const int c = l & 15, nh = l >> 4;

#pragma unroll
    for (int qq = 0; qq < 4; ++qq) {
        const int r  = qq * 32 + w * 8 + (l >> 3);
        const int cl = (l & 7) ^ (r & 7);
        gl_lds16(q + (Mbase + r) * 512 + h * 64 + cl * 8,
                 &qS[(qq * 32 + w * 8) * 64]);
    }
    __syncthreads();

    const unsigned short* pB = ktvB + (size_t)bh * 8192 + (size_t)l * 8;

    f32x4 acc[2][4];
#pragma unroll
    for (int i = 0; i < 2; ++i)
#pragma unroll
        for (int j = 0; j < 4; ++j) acc[i][j] = f32x4{0.f, 0.f, 0.f, 0.f};

#pragma unroll
    for (int ks = 0; ks < 4; ++ks) {
        short8 aF[2], bF[4];
#pragma unroll
        for (int it = 0; it < 2; ++it) {
            const int ra   = w * 32 + it * 16 + c;
            const int phys = (((ks & 1) * 4) + nh) ^ (c & 7);
            aF[it] = *(const short8*)&qS[ra * 64 + phys * 8];
        }
#pragma unroll
        for (int jt = 0; jt < 4; ++jt)
            bF[jt] = *(const short8*)(pB + (size_t)(jt * 4 + ks) * 512);
#pragma unroll
        for (int it = 0; it < 2; ++it)
#pragma unroll
            for (int jt = 0; jt < 4; ++jt)
                acc[it][jt] = MFMA_BF16(aF[it], bF[jt], acc[it][jt], 0, 0, 0);
    }

#pragma unroll
    for (int it = 0; it < 2; ++it)
#pragma unroll
        for (int jt = 0; jt < 4; ++jt)
#pragma unroll
            for (int r = 0; r < 4; ++r) {
                const size_t row = Mbase + w * 32 + it * 16 + nh * 4 + r;
                o[row * 512 + h * 64 + jt * 16 + c] =
                    f2bf(fmaxf(acc[it][jt][r], 0.f));
            }
}

extern "C" void kernel_launch(void* const* d_in, const int* in_sizes, int n_in,
                              void* d_out, int out_size, void* d_ws, size_t ws_size,
                              hipStream_t stream)
{
    (void)in_sizes; (void)n_in; (void)out_size; (void)ws_size;
    const float* x = (const float*)d_in[0];
    auto P = [&](int i) { return (const float*)d_in[i]; };

    char* wsb = (char*)d_ws;
    const size_t MB = 1024 * 1024;
    auto US = [&](size_t off) { return (unsigned short*)(wsb + off); };

    unsigned short* Wqkv = US(0);
    unsigned short* Wp   = US(2 * MB);
    unsigned short* W1   = US(3 * MB);
    unsigned short* W2   = US(5 * MB);

    float* bn = (float*)(wsb + 7 * MB);
    float* sc_qkv = bn;          float* sh_qkv = bn + 1536;
    float* sc_p = bn + 3072;     float* sh_p = bn + 3584;
    float* sc_1 = bn + 4096;     float* sh_1 = bn + 6144;
    float* sc_2 = bn + 8192;     float* sh_2 = bn + 8704;

    unsigned short* xb = US(8 * MB);
    unsigned short* qb = US(25 * MB);      // o aliases q
    unsigned short* kb = US(42 * MB);
    unsigned short* vb = US(59 * MB);
    unsigned short* hb = US(76 * MB);
    unsigned short* x1 = xb;
    unsigned short* ktvB = US(150 * MB);

    prep_bn<<<2, 256, 0, stream>>>(P(2),  P(3),  P(4),  P(5),  P(6),  sc_qkv,        sh_qkv,        512);
    prep_bn<<<2, 256, 0, stream>>>(P(8),  P(9),  P(10), P(11), P(12), sc_qkv + 512,  sh_qkv + 512,  512);
    prep_bn<<<2, 256, 0, stream>>>(P(14), P(15), P(16), P(17), P(18), sc_qkv + 1024, sh_qkv + 1024, 512);
    prep_bn<<<2, 256, 0, stream>>>(P(20), P(21), P(22), P(23), P(24), sc_p, sh_p, 512);
    prep_bn<<<8, 256, 0, stream>>>(P(26), P(27), P(28), P(29), P(30), sc_1, sh_1, 2048);
    prep_bn<<<2, 256, 0, stream>>>(P(32), P(33), P(34), P(35), P(36), sc_2, sh_2, 512);

    to_bf16<<<4096, 256, 0, stream>>>(x, xb, 16384 * 512 / 8);

    prep_w<<<128, 256, 0, stream>>>(P(1),  Wqkv,          512, 512);
    prep_w<<<128, 256, 0, stream>>>(P(7),  Wqkv + 262144, 512, 512);
    prep_w<<<128, 256, 0, stream>>>(P(13), Wqkv + 524288, 512, 512);
    prep_w<<<128, 256, 0, stream>>>(P(19), Wp, 512, 512);
    prep_w<<<512, 256, 0, stream>>>(P(25), W1, 2048, 512);
    prep_w<<<512, 256, 0, stream>>>(P(31), W2, 512, 2048);

    const dim3 blk(256);

    gemm_bf16<128, 0, 2><<<dim3(12, 128), blk, 0, stream>>>(
        xb, Wqkv, sc_qkv, sh_qkv, nullptr, nullptr,
        nullptr, nullptr, qb, kb, vb, 16384, 1536, 512);

    attn_kv<<<256, 64, 0, stream>>>(kb, vb, ktvB);
    attn_qo<<<1024, blk, 0, stream>>>(qb, ktvB, qb);   // o -> qb

    // x1 = bf16(x) + relu(bn(o @ p_w^T))  -- residual from xb (bf16)
    gemm_bf16<64, 2, 0><<<dim3(8, 128), blk, 0, stream>>>(
        qb, Wp, sc_p, sh_p, nullptr, xb,
        nullptr, x1, nullptr, nullptr, nullptr, 16384, 512, 512);

    gemm_bf16<128, 0, 0><<<dim3(16, 128), blk, 0, stream>>>(
        x1, W1, sc_1, sh_1, nullptr, nullptr,
        nullptr, hb, nullptr, nullptr, nullptr, 16384, 2048, 512);

    gemm_bf16<64, 2, 1><<<dim3(8, 128), blk, 0, stream>>>(
        hb, W2, sc_2, sh_2, nullptr, x1,
        (float*)d_out, nullptr, nullptr, nullptr, nullptr, 16384, 512, 2048);
}